// Round 5
// baseline (130.881 us; speedup 1.0000x reference)
//
#include <hip/hip_runtime.h>

#define B 512
#define D 256
#define NCLS 10
#define MARGIN 0.2f
#define THREADS 256
#define NWAVES (THREADS / 64)
#define ROWS 2
#define NBLOCKS (B / ROWS)

// Single fused kernel, 256 blocks x 256 threads (1 block/CU), 2 anchor rows
// per block. Sim phase is WAVE-PER-COLUMN: the wave's 64 lanes read one row
// of F as 64 consecutive float4s (one coalesced 1 KB transaction per
// instruction) — this replaces R4's thread-per-column pattern whose lanes
// hit 64 scattered cache lines per load (the 41 us stall). Anchor fragments
// live in registers (loop-invariant). Dots finish with a folded butterfly:
// both rows reduced with 7 shuffles/column.
__global__ __launch_bounds__(THREADS) void fused_loss_kernel(
    const float* __restrict__ F, const int* __restrict__ labels,
    float* __restrict__ out)
{
    __shared__ float simrow[ROWS][B];
    __shared__ int   lbl[B];
    __shared__ float pos_vals[B];
    __shared__ float neg_vals[B];
    __shared__ int   cnt[2];
    __shared__ int   hist[NCLS];
    __shared__ float wred[NWAVES];
    __shared__ int   vred[NWAVES];

    const int t    = threadIdx.x;
    const int lane = t & 63;
    const int w    = t >> 6;
    const int i0   = blockIdx.x * ROWS;

    // stage labels; zero histogram
    lbl[t]       = labels[t];
    lbl[t + 256] = labels[t + 256];
    if (t < NCLS) hist[t] = 0;
    __syncthreads();

    // label histogram (10 bins, LDS atomics)
    atomicAdd(&hist[lbl[t]], 1);
    atomicAdd(&hist[lbl[t + 256]], 1);

    // anchor fragments in registers: lane holds elements [4*lane, 4*lane+4)
    // of each anchor row (coalesced b128 loads)
    const float4 a0 = ((const float4*)(F + (size_t)(i0 + 0) * D))[lane];
    const float4 a1 = ((const float4*)(F + (size_t)(i0 + 1) * D))[lane];

    // wave w computes sim columns j = w + NWAVES*c (waves interleaved for
    // L1/L2 locality). Per column: one coalesced 1 KB row read + 8 FMAs +
    // folded 7-shuffle butterfly (lanes 0-31 end with row0 sum, 32-63 row1).
#pragma unroll 4
    for (int c = 0; c < B / NWAVES; ++c) {
        const int j = c * NWAVES + w;
        const float4 b = ((const float4*)(F + (size_t)j * D))[lane];
        float p0 = fmaf(b.x, a0.x, fmaf(b.y, a0.y, fmaf(b.z, a0.z, b.w * a0.w)));
        float p1 = fmaf(b.x, a1.x, fmaf(b.y, a1.y, fmaf(b.z, a1.z, b.w * a1.w)));
        p0 += __shfl_xor(p0, 32, 64);             // fold 64 -> 32 (row 0)
        p1 += __shfl_xor(p1, 32, 64);             // fold 64 -> 32 (row 1)
        float q = (lane & 32) ? p1 : p0;          // halves carry different rows
#pragma unroll
        for (int off = 16; off > 0; off >>= 1)    // butterfly stays in-half
            q += __shfl_xor(q, off, 64);
        if ((lane & 31) == 0) simrow[lane >> 5][j] = q;
    }
    __syncthreads();  // covers simrow writes AND histogram adds

    // num_valid contribution: row j valid iff 2 <= c[l_j] <= B-1
    {
        const int ca = hist[lbl[t]];
        const int cb = hist[lbl[t + 256]];
        const unsigned long long ma = __ballot(ca >= 2 && ca <= B - 1);
        const unsigned long long mb = __ballot(cb >= 2 && cb <= B - 1);
        if (lane == 0) vred[w] = __popcll(ma) + __popcll(mb);
    }

    float local = 0.f;
    for (int r = 0; r < ROWS; ++r) {
        const int i  = i0 + r;
        const int li = lbl[i];
        if (t == 0) { cnt[0] = 0; cnt[1] = 0; }
        __syncthreads();
        // partition row i into pos/neg lists; wave-ballot compaction
#pragma unroll
        for (int j2 = 0; j2 < 2; ++j2) {
            const int j = t + j2 * 256;
            const bool active = (j != i);
            const bool ispos  = active && (lbl[j] == li);
            const bool isneg  = active && (lbl[j] != li);
            const unsigned long long mp = __ballot(ispos);
            const unsigned long long mn = __ballot(isneg);
            int basep = 0, basen = 0;
            if (lane == 0) {
                basep = atomicAdd(&cnt[0], __popcll(mp));
                basen = atomicAdd(&cnt[1], __popcll(mn));
            }
            basep = __shfl(basep, 0, 64);
            basen = __shfl(basen, 0, 64);
            const unsigned long long below = (1ull << lane) - 1ull;
            if (ispos) pos_vals[basep + __popcll(mp & below)] = simrow[r][j];
            if (isneg) neg_vals[basen + __popcll(mn & below)] = simrow[r][j];
        }
        __syncthreads();
        const int P = cnt[0], N = cnt[1];
        // sum_{p,n} relu(margin + s_n - s_p)
        for (int pi = 0; pi < P; ++pi) {
            const float pv = pos_vals[pi] - MARGIN;  // LDS broadcast
            for (int ni = t; ni < N; ni += THREADS) {
                const float v = neg_vals[ni] - pv;
                local += (v > 0.f) ? v : 0.f;
            }
        }
        __syncthreads();  // before cnt/pos/neg buffer reuse
    }

    // block reduction: wave64 shuffle, then across 4 waves via LDS
#pragma unroll
    for (int off = 32; off > 0; off >>= 1)
        local += __shfl_down(local, off, 64);
    if (lane == 0) wred[w] = local;
    __syncthreads();
    if (t == 0) {
        float s = 0.f;
        int   nv = 0;
#pragma unroll
        for (int k = 0; k < NWAVES; ++k) { s += wred[k]; nv += vred[k]; }
        const int   clast = hist[lbl[B - 1]];
        const float denom = (float)nv * (float)(clast - 1) * (float)(B - clast);
        atomicAdd(out, (denom > 0.f) ? s / denom : 0.f);
    }
}

extern "C" void kernel_launch(void* const* d_in, const int* in_sizes, int n_in,
                              void* d_out, int out_size, void* d_ws, size_t ws_size,
                              hipStream_t stream) {
    const float* F      = (const float*)d_in[0];   // [512, 256] fp32
    const int*   labels = (const int*)d_in[1];     // [512] int32
    float* out = (float*)d_out;
    (void)d_ws; (void)ws_size;

    fused_loss_kernel<<<NBLOCKS, THREADS, 0, stream>>>(F, labels, out);
}

// Round 6
// 82.863 us; speedup vs baseline: 1.5795x; 1.5795x over previous
//
#include <hip/hip_runtime.h>

#define B 512
#define D 256
#define NCLS 10
#define MARGIN 0.2f
#define THREADS 256
#define NWAVES (THREADS / 64)
#define ROWS 2
#define NBLOCKS (B / ROWS)
#define DT 32            // D-slice width per tile
#define NDT (D / DT)     // 8 tiles
#define JS 514           // padded j-stride for ldsT (even: float2-aligned, bank-spread)

// Single fused kernel, 256 blocks x 256 threads, 2 anchor rows per block.
// Sim phase: D-sliced transposed-LDS tiles.
//  - stage F[:, dt:dt+DT] into ldsT[d][j] (transposed, j-stride 514):
//    global reads are 128B-aligned row segments (16 cache lines / wave
//    instruction — dense); LDS writes ~2-way conflicts (free).
//  - thread t owns sim columns 2t, 2t+1: reads ldsT[e][2t] as float2
//    (consecutive lanes -> consecutive banks) + anchor values via b128
//    broadcast; accumulates 4 dots in registers across tiles.
// No cross-lane ops anywhere in the sim phase (R5's 80us mistake), no
// 1KB-strided global loads (R1-R4's 40us mistake).
__global__ __launch_bounds__(THREADS) void fused_loss_kernel(
    const float* __restrict__ F, const int* __restrict__ labels,
    float* __restrict__ out)
{
    __shared__ float ldsT[DT * JS];       // 65.8 KB transposed F slice
    __shared__ float fi[ROWS][D];         // anchor rows
    __shared__ float simrow[ROWS][B];
    __shared__ int   lbl[B];
    __shared__ float pos_vals[B];
    __shared__ float neg_vals[B];
    __shared__ int   cnt[2];
    __shared__ int   hist[NCLS];
    __shared__ float wred[NWAVES];
    __shared__ int   vred[NWAVES];

    const int t    = threadIdx.x;
    const int lane = t & 63;
    const int w    = t >> 6;
    const int i0   = blockIdx.x * ROWS;

    // stage labels, anchor rows (coalesced float4), zero histogram
    lbl[t]       = labels[t];
    lbl[t + 256] = labels[t + 256];
    if (t < NCLS) hist[t] = 0;
    if (t < (ROWS * D) / 4)
        ((float4*)fi)[t] = ((const float4*)(F + (size_t)i0 * D))[t];
    __syncthreads();

    // label histogram (10 bins, LDS atomics); consumed much later
    atomicAdd(&hist[lbl[t]], 1);
    atomicAdd(&hist[lbl[t + 256]], 1);

    // ---- sim phase: 8 D-tiles, register accumulation ----
    float acc00 = 0.f, acc01 = 0.f, acc10 = 0.f, acc11 = 0.f;
    const float4* Fv = (const float4*)F;
    for (int tile = 0; tile < NDT; ++tile) {
        const int dt4 = tile * (DT / 4);
        // stage: slice = 512 rows x 8 float4; thread handles 16 float4s.
        // g -> row g>>3, chunk m=g&7; write transposed (4 scalar writes).
#pragma unroll
        for (int k = 0; k < (B * DT / 4) / THREADS; ++k) {
            const int g   = t + THREADS * k;
            const int row = g >> 3;
            const int m   = g & 7;
            const float4 v = Fv[row * (D / 4) + dt4 + m];
            ldsT[(4 * m + 0) * JS + row] = v.x;
            ldsT[(4 * m + 1) * JS + row] = v.y;
            ldsT[(4 * m + 2) * JS + row] = v.z;
            ldsT[(4 * m + 3) * JS + row] = v.w;
        }
        __syncthreads();
        // compute: cols 2t, 2t+1 vs both anchor rows
        const int dt = tile * DT;
#pragma unroll
        for (int e4 = 0; e4 < DT / 4; ++e4) {
            const float4 a0 = *(const float4*)&fi[0][dt + 4 * e4];  // broadcast
            const float4 a1 = *(const float4*)&fi[1][dt + 4 * e4];  // broadcast
#pragma unroll
            for (int q = 0; q < 4; ++q) {
                const float2 x = *(const float2*)&ldsT[(4 * e4 + q) * JS + 2 * t];
                const float a0q = q == 0 ? a0.x : q == 1 ? a0.y : q == 2 ? a0.z : a0.w;
                const float a1q = q == 0 ? a1.x : q == 1 ? a1.y : q == 2 ? a1.z : a1.w;
                acc00 = fmaf(a0q, x.x, acc00);
                acc01 = fmaf(a0q, x.y, acc01);
                acc10 = fmaf(a1q, x.x, acc10);
                acc11 = fmaf(a1q, x.y, acc11);
            }
        }
        __syncthreads();  // before next tile's staging overwrites ldsT
    }
    *(float2*)&simrow[0][2 * t] = make_float2(acc00, acc01);
    *(float2*)&simrow[1][2 * t] = make_float2(acc10, acc11);
    __syncthreads();  // simrow visible (histogram long since done)

    // num_valid contribution: row j valid iff 2 <= c[l_j] <= B-1
    {
        const int ca = hist[lbl[t]];
        const int cb = hist[lbl[t + 256]];
        const unsigned long long ma = __ballot(ca >= 2 && ca <= B - 1);
        const unsigned long long mb = __ballot(cb >= 2 && cb <= B - 1);
        if (lane == 0) vred[w] = __popcll(ma) + __popcll(mb);
    }

    // ---- hinge phase (unchanged structure; thread t covers j=2t,2t+1) ----
    float local = 0.f;
    for (int r = 0; r < ROWS; ++r) {
        const int i  = i0 + r;
        const int li = lbl[i];
        if (t == 0) { cnt[0] = 0; cnt[1] = 0; }
        __syncthreads();
#pragma unroll
        for (int h = 0; h < 2; ++h) {
            const int j = 2 * t + h;
            const bool active = (j != i);
            const bool ispos  = active && (lbl[j] == li);
            const bool isneg  = active && (lbl[j] != li);
            const unsigned long long mp = __ballot(ispos);
            const unsigned long long mn = __ballot(isneg);
            int basep = 0, basen = 0;
            if (lane == 0) {
                basep = atomicAdd(&cnt[0], __popcll(mp));
                basen = atomicAdd(&cnt[1], __popcll(mn));
            }
            basep = __shfl(basep, 0, 64);
            basen = __shfl(basen, 0, 64);
            const unsigned long long below = (1ull << lane) - 1ull;
            if (ispos) pos_vals[basep + __popcll(mp & below)] = simrow[r][j];
            if (isneg) neg_vals[basen + __popcll(mn & below)] = simrow[r][j];
        }
        __syncthreads();
        const int P = cnt[0], N = cnt[1];
        // sum_{p,n} relu(margin + s_n - s_p)
        for (int pi = 0; pi < P; ++pi) {
            const float pv = pos_vals[pi] - MARGIN;  // LDS broadcast
            for (int ni = t; ni < N; ni += THREADS) {
                const float v = neg_vals[ni] - pv;
                local += (v > 0.f) ? v : 0.f;
            }
        }
        __syncthreads();  // before cnt/pos/neg buffer reuse
    }

    // block reduction: wave64 shuffle, then across 4 waves via LDS
#pragma unroll
    for (int off = 32; off > 0; off >>= 1)
        local += __shfl_down(local, off, 64);
    if (lane == 0) wred[w] = local;
    __syncthreads();
    if (t == 0) {
        float s = 0.f;
        int   nv = 0;
#pragma unroll
        for (int k = 0; k < NWAVES; ++k) { s += wred[k]; nv += vred[k]; }
        const int   clast = hist[lbl[B - 1]];
        const float denom = (float)nv * (float)(clast - 1) * (float)(B - clast);
        atomicAdd(out, (denom > 0.f) ? s / denom : 0.f);
    }
}

extern "C" void kernel_launch(void* const* d_in, const int* in_sizes, int n_in,
                              void* d_out, int out_size, void* d_ws, size_t ws_size,
                              hipStream_t stream) {
    const float* F      = (const float*)d_in[0];   // [512, 256] fp32
    const int*   labels = (const int*)d_in[1];     // [512] int32
    float* out = (float*)d_out;
    (void)d_ws; (void)ws_size;

    fused_loss_kernel<<<NBLOCKS, THREADS, 0, stream>>>(F, labels, out);
}